// Round 4
// baseline (140.298 us; speedup 1.0000x reference)
//
#include <hip/hip_runtime.h>
#include <hip/hip_bf16.h>

typedef __bf16 bf16x4  __attribute__((ext_vector_type(4)));
typedef __bf16 bf16x8  __attribute__((ext_vector_type(8)));
typedef __bf16 bf16x16 __attribute__((ext_vector_type(16)));
typedef float  f32x4   __attribute__((ext_vector_type(4)));
typedef unsigned short u16x8 __attribute__((ext_vector_type(8)));

#define N_IN   4096
#define N_OUT  1024
#define BATCH  16
#define ROWS   16     // fallback kernel tile

// LDS strides in __bf16 elements
#define H1_STR   72
#define H2_STR   72
#define FT_JSTR  40     // i-stride inside a j-slot row
#define FTH_NSTR 648    // per-n stride (16 j * 40 + 8 pad)
#define G_STR    520    // fallback
#define V_STR    520    // fallback
#define GSTR2    1048   // gb stride (1024 + 24)
#define FB_FT_NSTR 1288 // fallback
#define SEG_STR  40     // seg per-window stride: 80B -> 16B-aligned b128 reads,
                        // 16 lanes/address broadcast in phase E (conflict-free)
#define WSLAB    2592   // per-wave vals slab = 4 * FTH_NSTR (wave-private after S5)

// ws layout:
//   [0,131072)       w3t  bf16 (1024x64)       w3t[col*64+k]
//   [131072,139264)  w2t  bf16 (64x64)         w2t[col*64+k]
//   [139264,4333568) featT bf16 (32*4096*16)   featT[((c*4096+src)*16)+b]
#define WS_W3T_OFF    0
#define WS_W2T_OFF    131072
#define WS_FEATT_OFF  139264
#define WS_NEED       4333568

__global__ void qc_zero_kernel(float* __restrict__ out, int n4) {
    int i = blockIdx.x * blockDim.x + threadIdx.x;
    if (i < n4) ((float4*)out)[i] = make_float4(0.f, 0.f, 0.f, 0.f);
}

__global__ void qc_prep_kernel(const float* __restrict__ w3, const float* __restrict__ w2,
                               __bf16* __restrict__ w3t, __bf16* __restrict__ w2t) {
    int gid = blockIdx.x * blockDim.x + threadIdx.x;
    if (gid < 65536) {
        int k = gid & 63, col = gid >> 6;
        w3t[gid] = (__bf16)w3[k * 1024 + col];
    } else {
        int j = gid - 65536;
        int k = j & 63, col = j >> 6;
        w2t[j] = (__bf16)w2[k * 64 + col];
    }
}

// Fused prep: heavy blocks first (featT 0..511, w3t 512..527, w2t 528),
// trivial zero blocks last. w3t transpose via LDS tile (coalesced both ways).
__global__ void qc_prep2_kernel(const float* __restrict__ w3, const float* __restrict__ w2,
                                const float* __restrict__ feat,
                                float* __restrict__ out,
                                __bf16* __restrict__ w3t, __bf16* __restrict__ w2t,
                                __bf16* __restrict__ featT) {
    int bid = blockIdx.x, tid = threadIdx.x;
    if (bid < 512) {
        int c    = bid >> 4;                         // 0..31
        int src  = (bid & 15) * 256 + tid;           // 0..4095
        bf16x16 v;
        #pragma unroll
        for (int b = 0; b < 16; ++b)
            v[b] = (__bf16)feat[(b * 32 + c) * N_IN + src];
        __bf16* p = &featT[((size_t)c * N_IN + src) * 16];
        *(bf16x8*)p       = *(bf16x8*)&v;
        *(bf16x8*)(p + 8) = *((bf16x8*)&v + 1);
    } else if (bid < 528) {
        __shared__ float tile[64][65];
        const int colbase = (bid - 512) * 64;
        #pragma unroll
        for (int it = 0; it < 16; ++it) {
            int k = it * 4 + (tid >> 6);
            int c = tid & 63;
            tile[k][c] = w3[k * 1024 + colbase + c];
        }
        __syncthreads();
        int cc = tid >> 2;
        int k0 = (tid & 3) * 16;
        bf16x8 o0, o1;
        #pragma unroll
        for (int z = 0; z < 8; ++z) {
            o0[z] = (__bf16)tile[k0 + z][cc];
            o1[z] = (__bf16)tile[k0 + 8 + z][cc];
        }
        __bf16* wp = &w3t[(colbase + cc) * 64 + k0];
        *(bf16x8*)wp       = o0;
        *(bf16x8*)(wp + 8) = o1;
    } else if (bid == 528) {
        #pragma unroll
        for (int z = 0; z < 16; ++z) {
            int j = tid * 16 + z;
            w2t[j] = (__bf16)w2[(j & 63) * 64 + (j >> 6)];
        }
    } else {
        int i = (bid - 529) * 256 + tid;
        ((float4*)out)[i] = make_float4(0.f, 0.f, 0.f, 0.f);
    }
}

// ---------------------------------------------------------------------------
// Fused 32-row kernel, V5 (barrier diet: 7 -> 5):
//   After S5 the ftv/vals region partitions into 8 wave-private 5184B slabs:
//   wave wv's D-rows [4wv,4wv+4) == its vals slab == its Phase-E read range,
//   and seg windows [4wv,4wv+4) are written by wave wv itself. So D-pass1
//   (f1 reads -> c1 MFMA -> vals writes) and the whole Phase-E scan run
//   with NO barriers (same-wave LDS ops are in-order). S6/S7 deleted.
//   Phase E re-mapped: lane -> (b = lane&15, w = 4*wv + (lane>>4)).
//   Seg reads vectorized: 4x ds_read_b128 (SEG_STR=40, 16B-aligned,
//   16 lanes/address broadcast).
// ---------------------------------------------------------------------------
__global__ __launch_bounds__(512, 2)
void qc_fused32_kernel(const __bf16* __restrict__ featT,
                       const float* __restrict__ w1,
                       const float* __restrict__ locs,
                       const int*   __restrict__ eidx,
                       const __bf16* __restrict__ w2t,
                       const __bf16* __restrict__ w3t,
                       float* __restrict__ out,
                       int E)
{
    __shared__ __align__(16) unsigned char region1[41472]; // gb/ftv/vals
    __shared__ __align__(16) __bf16 h1b[32 * H1_STR];      // 4608 B
    __shared__ __align__(16) __bf16 h2b[32 * H2_STR];      // 4608 B
    __shared__ __align__(16) unsigned short seg_s[32 * SEG_STR]; // 2560 B
    // total 53248 B raw -> 3 blocks/CU still fits (3x53248 = 159744 <= 163840)

    __bf16* gb   = (__bf16*)region1;   // [b][tl] stride GSTR2   (33536 B)
    __bf16* ftv  = (__bf16*)region1;   // [n:32][jslot:16*40+8]  (41472 B)
    __bf16* vals = (__bf16*)region1;   // 8 wave slabs of WSLAB elems

    const int tid  = threadIdx.x;
    const int lane = tid & 63;
    const int wv   = tid >> 6;      // 0..7
    const int ml   = lane & 15;
    const int q    = lane >> 4;
    const int n0   = blockIdx.x * 32;
    const int t0   = n0 * 32;
    const int ch0  = t0 / E;
    const int m0   = t0 - ch0 * E;     // block spans <1024 t's -> at most one wrap

    // ---- Gather (wave-owned slots) + top-of-block weight loads ----
    const int tlb = wv * 128 + lane;
    bf16x16 gvv[2];
    int sgv[2];
    #pragma unroll
    for (int h = 0; h < 2; ++h) {
        int tl = tlb + h * 64;
        int mm = m0 + tl;
        int cc = ch0 + (mm >= E);
        if (mm >= E) mm -= E;
        int2 p = ((const int2*)eidx)[mm];      // .x = seg, .y = src
        sgv[h] = p.x;
        int ccc = cc < 32 ? cc : 31;
        bf16x16 g = *(const bf16x16*)&featT[((size_t)ccc * N_IN + p.y) * 16];
        if (cc >= 32) {
            #pragma unroll
            for (int z = 0; z < 16; ++z) g[z] = (__bf16)0.f;
        }
        gvv[h] = g;
    }
    // Phase-B weights, issued early so L2 latency hides under Phase A
    const int rg = (wv >> 2) * 16;
    const int cw = (wv & 3) * 16;
    const bf16x8 bw0 = *(const bf16x8*)&w2t[(cw + ml) * 64 + q * 8];
    const bf16x8 bw1 = *(const bf16x8*)&w2t[(cw + ml) * 64 + 32 + q * 8];

    // ---- Phase A: h1 = sin(loc @ W1) ----
    {
        const int r  = tid >> 4;               // 0..31
        const int j0 = (tid & 15) * 4;
        float lx = 0.f, ly = 0.f;
        int n = n0 + r;
        if (n < E) { lx = locs[n * 2]; ly = locs[n * 2 + 1]; }
        float4 wa = *(const float4*)&w1[j0];
        float4 wb = *(const float4*)&w1[64 + j0];
        __bf16* hp = &h1b[r * H1_STR + j0];
        hp[0] = (__bf16)__sinf(lx * wa.x + ly * wb.x);
        hp[1] = (__bf16)__sinf(lx * wa.y + ly * wb.y);
        hp[2] = (__bf16)__sinf(lx * wa.z + ly * wb.z);
        hp[3] = (__bf16)__sinf(lx * wa.w + ly * wb.w);
    }
    __syncthreads();   // S1

    // ---- Phase B: h2 = sin(h1 @ W2) ----
    {
        bf16x8 a0 = *(const bf16x8*)&h1b[(rg + ml) * H1_STR + q * 8];
        bf16x8 a1 = *(const bf16x8*)&h1b[(rg + ml) * H1_STR + 32 + q * 8];
        f32x4 c = {0.f, 0.f, 0.f, 0.f};
        c = __builtin_amdgcn_mfma_f32_16x16x32_bf16(a0, bw0, c, 0, 0, 0);
        c = __builtin_amdgcn_mfma_f32_16x16x32_bf16(a1, bw1, c, 0, 0, 0);
        #pragma unroll
        for (int g_ = 0; g_ < 4; ++g_)
            h2b[(rg + q * 4 + g_) * H2_STR + cw + ml] = (__bf16)__sinf(c[g_]);
    }

    // ---- Park own gather + seg (own windows); preload A-frags (same-wave) ----
    #pragma unroll
    for (int b = 0; b < 16; ++b) {
        gb[b * GSTR2 + tlb]      = gvv[0][b];
        gb[b * GSTR2 + tlb + 64] = gvv[1][b];
    }
    seg_s[(tlb >> 5) * SEG_STR + (tlb & 31)] = (unsigned short)sgv[0];
    {
        int tl1 = tlb + 64;
        seg_s[(tl1 >> 5) * SEG_STR + (tl1 & 31)] = (unsigned short)sgv[1];
    }
    bf16x8 ag[4];
    #pragma unroll
    for (int rr = 0; rr < 4; ++rr)
        ag[rr] = *(const bf16x8*)&gb[ml * GSTR2 + (wv * 4 + rr) * 32 + q * 8];
    __syncthreads();   // S2: h2b ready; ag preloads done; region becomes ftv

    bf16x8 ha00 = *(const bf16x8*)&h2b[ml * H2_STR + q * 8];
    bf16x8 ha01 = *(const bf16x8*)&h2b[ml * H2_STR + 32 + q * 8];
    bf16x8 ha10 = *(const bf16x8*)&h2b[(16 + ml) * H2_STR + q * 8];
    bf16x8 ha11 = *(const bf16x8*)&h2b[(16 + ml) * H2_STR + 32 + q * 8];

    f32x4 c0[4], c1[4];

    // ---- C-pass0: filt cols j<16, acc in regs, 8x b64 writes ----
    {
        f32x4 accA[4], accB[4];
        #pragma unroll
        for (int tt = 0; tt < 4; ++tt) {
            int i_  = wv * 4 + tt;
            int col = i_ * 32 + ml;            // j = ml < 16
            const __bf16* wp = &w3t[col * 64 + q * 8];
            bf16x8 b0 = *(const bf16x8*)wp;
            bf16x8 b1 = *(const bf16x8*)(wp + 32);
            f32x4 cA = {0.f, 0.f, 0.f, 0.f};
            f32x4 cB = {0.f, 0.f, 0.f, 0.f};
            cA = __builtin_amdgcn_mfma_f32_16x16x32_bf16(ha00, b0, cA, 0, 0, 0);
            cA = __builtin_amdgcn_mfma_f32_16x16x32_bf16(ha01, b1, cA, 0, 0, 0);
            cB = __builtin_amdgcn_mfma_f32_16x16x32_bf16(ha10, b0, cB, 0, 0, 0);
            cB = __builtin_amdgcn_mfma_f32_16x16x32_bf16(ha11, b1, cB, 0, 0, 0);
            accA[tt] = cA; accB[tt] = cB;
        }
        #pragma unroll
        for (int g_ = 0; g_ < 4; ++g_) {
            bf16x4 pa, pb;
            #pragma unroll
            for (int tt = 0; tt < 4; ++tt) {
                pa[tt] = (__bf16)accA[tt][g_];
                pb[tt] = (__bf16)accB[tt][g_];
            }
            *(bf16x4*)&ftv[(q * 4 + g_) * FTH_NSTR + ml * FT_JSTR + wv * 4]        = pa;
            *(bf16x4*)&ftv[(16 + q * 4 + g_) * FTH_NSTR + ml * FT_JSTR + wv * 4]   = pb;
        }
    }
    __syncthreads();   // S3

    // ---- D-pass0: vals j<16; wave handles its own rows wv*4..+4 ----
    {
        bf16x8 f[4];
        #pragma unroll
        for (int rr = 0; rr < 4; ++rr)
            f[rr] = *(const bf16x8*)&ftv[(wv * 4 + rr) * FTH_NSTR + ml * FT_JSTR + q * 8];
        #pragma unroll
        for (int rr = 0; rr < 4; ++rr) {
            f32x4 z = {0.f, 0.f, 0.f, 0.f};
            c0[rr] = __builtin_amdgcn_mfma_f32_16x16x32_bf16(ag[rr], f[rr], z, 0, 0, 0);
        }
    }
    __syncthreads();   // S4 (ftv reads done)

    // ---- C-pass1: filt cols j>=16 (overwrite ftv) ----
    {
        f32x4 accA[4], accB[4];
        #pragma unroll
        for (int tt = 0; tt < 4; ++tt) {
            int i_  = wv * 4 + tt;
            int col = i_ * 32 + 16 + ml;       // j = 16 + ml
            const __bf16* wp = &w3t[col * 64 + q * 8];
            bf16x8 b0 = *(const bf16x8*)wp;
            bf16x8 b1 = *(const bf16x8*)(wp + 32);
            f32x4 cA = {0.f, 0.f, 0.f, 0.f};
            f32x4 cB = {0.f, 0.f, 0.f, 0.f};
            cA = __builtin_amdgcn_mfma_f32_16x16x32_bf16(ha00, b0, cA, 0, 0, 0);
            cA = __builtin_amdgcn_mfma_f32_16x16x32_bf16(ha01, b1, cA, 0, 0, 0);
            cB = __builtin_amdgcn_mfma_f32_16x16x32_bf16(ha10, b0, cB, 0, 0, 0);
            cB = __builtin_amdgcn_mfma_f32_16x16x32_bf16(ha11, b1, cB, 0, 0, 0);
            accA[tt] = cA; accB[tt] = cB;
        }
        #pragma unroll
        for (int g_ = 0; g_ < 4; ++g_) {
            bf16x4 pa, pb;
            #pragma unroll
            for (int tt = 0; tt < 4; ++tt) {
                pa[tt] = (__bf16)accA[tt][g_];
                pb[tt] = (__bf16)accB[tt][g_];
            }
            *(bf16x4*)&ftv[(q * 4 + g_) * FTH_NSTR + ml * FT_JSTR + wv * 4]        = pa;
            *(bf16x4*)&ftv[(16 + q * 4 + g_) * FTH_NSTR + ml * FT_JSTR + wv * 4]   = pb;
        }
    }
    __syncthreads();   // S5 -- LAST barrier: region now wave-private slabs

    // ---- D-pass1 + vals writes + Phase E: all same-wave, no barriers ----
    {
        bf16x8 f1[4];
        #pragma unroll
        for (int rr = 0; rr < 4; ++rr)
            f1[rr] = *(const bf16x8*)&ftv[(wv * 4 + rr) * FTH_NSTR + ml * FT_JSTR + q * 8];
        #pragma unroll
        for (int rr = 0; rr < 4; ++rr) {
            f32x4 z = {0.f, 0.f, 0.f, 0.f};
            c1[rr] = __builtin_amdgcn_mfma_f32_16x16x32_bf16(ag[rr], f1[rr], z, 0, 0, 0);
        }
        // write own slab (same range the f1 reads came from; LDS in-order/WAR-safe)
        __bf16* vslab = &vals[wv * WSLAB];
        #pragma unroll
        for (int rr = 0; rr < 4; ++rr) {
            __bf16* vp = &vslab[rr * FTH_NSTR];
            #pragma unroll
            for (int g_ = 0; g_ < 4; ++g_) {
                int b = q * 4 + g_;
                vp[b * FT_JSTR + ml]      = (__bf16)c0[rr][g_];
                vp[b * FT_JSTR + 16 + ml] = (__bf16)c1[rr][g_];
            }
        }

        // ---- Phase E: lane -> (b = lane&15, w = 4wv + lane>>4); all own-wave data ----
        const int q2 = lane >> 4;             // 0..3
        const int b  = lane & 15;
        const int w  = wv * 4 + q2;           // window index
        const __bf16* vp = &vslab[q2 * FTH_NSTR + b * FT_JSTR];
        bf16x8 v0 = *(const bf16x8*)(vp);
        bf16x8 v1 = *(const bf16x8*)(vp + 8);
        bf16x8 v2 = *(const bf16x8*)(vp + 16);
        bf16x8 v3 = *(const bf16x8*)(vp + 24);
        const u16x8* sp = (const u16x8*)&seg_s[w * SEG_STR];
        u16x8 s0 = sp[0], s1 = sp[1], s2 = sp[2], s3 = sp[3];

        float vv[32];
        #pragma unroll
        for (int j = 0; j < 8; ++j) {
            vv[j]      = (float)v0[j];
            vv[8 + j]  = (float)v1[j];
            vv[16 + j] = (float)v2[j];
            vv[24 + j] = (float)v3[j];
        }
        unsigned short ss[32];
        #pragma unroll
        for (int j = 0; j < 8; ++j) {
            ss[j]      = s0[j];
            ss[8 + j]  = s1[j];
            ss[16 + j] = s2[j];
            ss[24 + j] = s3[j];
        }
        int mwin = m0 + (w << 5);
        int cb   = ch0;
        if (mwin >= E) { mwin -= E; ++cb; }
        int jcross = E - mwin;                 // wrap inside window iff < 32
        int base0 = (cb < 32)     ? ((b << 15) | (cb << 10))       : -1;
        int base1 = (cb + 1 < 32) ? ((b << 15) | ((cb + 1) << 10)) : -1;
        int key_prev = -1;
        float acc = 0.f;
        #pragma unroll
        for (int j = 0; j < 32; ++j) {
            int basej = (j < jcross) ? base0 : base1;
            if (basej >= 0) {
                int key = basej + (int)ss[j];
                if (key != key_prev) {
                    if (key_prev >= 0) atomicAdd(&out[key_prev], acc);
                    key_prev = key;
                    acc = vv[j];
                } else {
                    acc += vv[j];
                }
            }
        }
        if (key_prev >= 0) atomicAdd(&out[key_prev], acc);
    }
}

// ---------------------------------------------------------------------------
// Fallback: round-1 fused kernel (used only if ws too small)
// ---------------------------------------------------------------------------
__global__ __launch_bounds__(256, 2)
void qc_main_kernel(const float* __restrict__ feat,
                    const float* __restrict__ w1,
                    const float* __restrict__ w2,
                    const float* __restrict__ locs,
                    const int*   __restrict__ eidx,
                    const __bf16* __restrict__ w3t,
                    float* __restrict__ out,
                    int E)
{
    __shared__ __align__(16) __bf16 h1b[ROWS * H1_STR];
    __shared__ __align__(16) __bf16 h2b[ROWS * H2_STR];
    __shared__ __align__(16) __bf16 ftv[ROWS * FB_FT_NSTR];
    __shared__ __align__(16) __bf16 gb [BATCH * G_STR];
    __shared__ unsigned short seg_s[512];
    __shared__ unsigned short src_s[512];

    const int tid = threadIdx.x;
    const int n0  = blockIdx.x * ROWS;
    const int t0  = n0 * 32;
    const int ch0 = t0 / E;
    const int m0  = t0 - ch0 * E;

    {
        const int r  = tid >> 4;
        const int j0 = (tid & 15) * 4;
        float lx = 0.f, ly = 0.f;
        int n = n0 + r;
        if (n < E) { lx = locs[n * 2]; ly = locs[n * 2 + 1]; }
        float4 wa = *(const float4*)&w1[j0];
        float4 wb = *(const float4*)&w1[64 + j0];
        __bf16* h = &h1b[r * H1_STR + j0];
        h[0] = (__bf16)__sinf(lx * wa.x + ly * wb.x);
        h[1] = (__bf16)__sinf(lx * wa.y + ly * wb.y);
        h[2] = (__bf16)__sinf(lx * wa.z + ly * wb.z);
        h[3] = (__bf16)__sinf(lx * wa.w + ly * wb.w);
    }
    for (int tl = tid; tl < 512; tl += 256) {
        int mm = m0 + tl; if (mm >= E) mm -= E;
        seg_s[tl] = (unsigned short)eidx[mm * 2];
        src_s[tl] = (unsigned short)eidx[mm * 2 + 1];
    }
    __syncthreads();

    {
        const int r  = tid >> 4;
        const int j0 = (tid & 15) * 4;
        float a0 = 0.f, a1 = 0.f, a2 = 0.f, a3 = 0.f;
        const __bf16* h1r = &h1b[r * H1_STR];
        #pragma unroll 8
        for (int k = 0; k < 64; ++k) {
            float h = (float)h1r[k];
            float4 w = *(const float4*)&w2[k * 64 + j0];
            a0 += h * w.x; a1 += h * w.y; a2 += h * w.z; a3 += h * w.w;
        }
        __bf16* h = &h2b[r * H2_STR + j0];
        h[0] = (__bf16)__sinf(a0);
        h[1] = (__bf16)__sinf(a1);
        h[2] = (__bf16)__sinf(a2);
        h[3] = (__bf16)__sinf(a3);
    }
    #pragma unroll 4
    for (int it = 0; it < 32; ++it) {
        int idx = it * 256 + tid;
        int b   = idx >> 9;
        int tl  = idx & 511;
        int mm  = m0 + tl;
        int cc  = ch0 + (mm >= E);
        if (mm >= E) mm -= E;
        float v = 0.f;
        if (cc < 32) v = feat[(b * 32 + cc) * N_IN + (int)src_s[tl]];
        gb[b * G_STR + tl] = (__bf16)v;
    }
    __syncthreads();

    const int lane = tid & 63;
    const int wv   = tid >> 6;
    const int ml   = lane & 15;
    const int q    = lane >> 4;

    {
        bf16x8 a0 = *(const bf16x8*)&h2b[ml * H2_STR + q * 8];
        bf16x8 a1 = *(const bf16x8*)&h2b[ml * H2_STR + 32 + q * 8];
        #pragma unroll
        for (int t = 0; t < 16; ++t) {
            int col = wv * 256 + t * 16 + ml;
            const __bf16* wp = &w3t[col * 64 + q * 8];
            bf16x8 b0 = *(const bf16x8*)wp;
            bf16x8 b1 = *(const bf16x8*)(wp + 32);
            f32x4 c = {0.f, 0.f, 0.f, 0.f};
            c = __builtin_amdgcn_mfma_f32_16x16x32_bf16(a0, b0, c, 0, 0, 0);
            c = __builtin_amdgcn_mfma_f32_16x16x32_bf16(a1, b1, c, 0, 0, 0);
            int i_ = col >> 5, j_ = col & 31;
            __bf16* fp = &ftv[j_ * FT_JSTR + i_];
            fp[(q * 4 + 0) * FB_FT_NSTR] = (__bf16)c[0];
            fp[(q * 4 + 1) * FB_FT_NSTR] = (__bf16)c[1];
            fp[(q * 4 + 2) * FB_FT_NSTR] = (__bf16)c[2];
            fp[(q * 4 + 3) * FB_FT_NSTR] = (__bf16)c[3];
        }
    }
    __syncthreads();

    {
        bf16x8 ag[4], f0[4], f1[4];
        #pragma unroll
        for (int rr = 0; rr < 4; ++rr) {
            int r = wv * 4 + rr;
            ag[rr] = *(const bf16x8*)&gb[ml * G_STR + r * 32 + q * 8];
            f0[rr] = *(const bf16x8*)&ftv[r * FB_FT_NSTR + ml        * FT_JSTR + q * 8];
            f1[rr] = *(const bf16x8*)&ftv[r * FB_FT_NSTR + (16 + ml) * FT_JSTR + q * 8];
        }
        __syncthreads();
        __bf16* valsb = ftv;
        #pragma unroll
        for (int rr = 0; rr < 4; ++rr) {
            int r = wv * 4 + rr;
            f32x4 c0 = {0.f, 0.f, 0.f, 0.f};
            f32x4 c1 = {0.f, 0.f, 0.f, 0.f};
            c0 = __builtin_amdgcn_mfma_f32_16x16x32_bf16(ag[rr], f0[rr], c0, 0, 0, 0);
            c1 = __builtin_amdgcn_mfma_f32_16x16x32_bf16(ag[rr], f1[rr], c1, 0, 0, 0);
            __bf16* vp = &valsb[r * 32];
            #pragma unroll
            for (int g_ = 0; g_ < 4; ++g_) {
                int b = q * 4 + g_;
                vp[b * V_STR + ml]      = (__bf16)c0[g_];
                vp[b * V_STR + 16 + ml] = (__bf16)c1[g_];
            }
        }
    }
    __syncthreads();

    {
        const __bf16* valsb = ftv;
        const int b = tid >> 4;
        const int r = tid & 15;
        const __bf16* vp = &valsb[b * V_STR + r * 32];
        bf16x8 v0 = *(const bf16x8*)(vp);
        bf16x8 v1 = *(const bf16x8*)(vp + 8);
        bf16x8 v2 = *(const bf16x8*)(vp + 16);
        bf16x8 v3 = *(const bf16x8*)(vp + 24);
        float vv[32];
        #pragma unroll
        for (int j = 0; j < 8; ++j) {
            vv[j]      = (float)v0[j];
            vv[8 + j]  = (float)v1[j];
            vv[16 + j] = (float)v2[j];
            vv[24 + j] = (float)v3[j];
        }
        const int tl0 = r * 32;
        int key_prev = -1;
        float acc = 0.f;
        #pragma unroll
        for (int j = 0; j < 32; ++j) {
            int mm = m0 + tl0 + j;
            int cc = ch0 + (mm >= E);
            if (mm >= E) mm -= E;
            if (cc < 32) {
                int o   = (int)seg_s[tl0 + j];
                int key = ((b * 32 + cc) << 10) | o;
                if (key != key_prev) {
                    if (key_prev >= 0) atomicAdd(&out[key_prev], acc);
                    key_prev = key;
                    acc = vv[j];
                } else {
                    acc += vv[j];
                }
            }
        }
        if (key_prev >= 0) atomicAdd(&out[key_prev], acc);
    }
}

extern "C" void kernel_launch(void* const* d_in, const int* in_sizes, int n_in,
                              void* d_out, int out_size, void* d_ws, size_t ws_size,
                              hipStream_t stream)
{
    (void)n_in;
    const float* feat = (const float*)d_in[0];
    const float* w1   = (const float*)d_in[1];
    const float* w2   = (const float*)d_in[2];
    const float* w3   = (const float*)d_in[3];
    const float* locs = (const float*)d_in[4];
    const int*   eidx = (const int*)d_in[5];
    float* out  = (float*)d_out;

    const int E = in_sizes[4] / 2;
    if (E <= 0) return;

    __bf16* w3t   = (__bf16*)((char*)d_ws + WS_W3T_OFF);
    __bf16* w2t   = (__bf16*)((char*)d_ws + WS_W2T_OFF);
    __bf16* featT = (__bf16*)((char*)d_ws + WS_FEATT_OFF);

    if (ws_size >= (size_t)WS_NEED) {
        int nblocks = (E + 31) / 32;
        qc_prep2_kernel<<<1041, 256, 0, stream>>>(w3, w2, feat, out, w3t, w2t, featT);
        qc_fused32_kernel<<<nblocks, 512, 0, stream>>>(featT, w1, locs, eidx, w2t, w3t, out, E);
    } else {
        int n4 = out_size / 4;
        int nblocks = (E + ROWS - 1) / ROWS;
        qc_zero_kernel<<<(n4 + 255) / 256, 256, 0, stream>>>(out, n4);
        qc_prep_kernel<<<272, 256, 0, stream>>>(w3, w2, w3t, w2t);
        qc_main_kernel<<<nblocks, 256, 0, stream>>>(feat, w1, w2, locs, eidx, w3t, out, E);
    }
}

// Round 5
// 127.264 us; speedup vs baseline: 1.1024x; 1.1024x over previous
//
#include <hip/hip_runtime.h>
#include <hip/hip_bf16.h>

typedef __bf16 bf16x4  __attribute__((ext_vector_type(4)));
typedef __bf16 bf16x8  __attribute__((ext_vector_type(8)));
typedef __bf16 bf16x16 __attribute__((ext_vector_type(16)));
typedef float  f32x4   __attribute__((ext_vector_type(4)));

#define N_IN   4096
#define N_OUT  1024
#define BATCH  16
#define ROWS   16     // fallback kernel tile

// LDS strides in __bf16 elements
#define H1_STR   72
#define H2_STR   72
#define FT_JSTR  40     // i-stride inside a j-slot row
#define FTH_NSTR 648    // per-n stride (16 j * 40 + 8 pad)
#define G_STR    520    // fallback
#define V_STR    520    // fallback
#define GSTR2    1048   // gb stride (1024 + 24)
#define VSTR2    1288   // vals per-b stride (32 w * 40)
#define FB_FT_NSTR 1288 // fallback
#define SEG_STR  34     // seg_s per-window stride: bank = 17*w + j/2 -> conflict-free
#define TILE_K   144    // dense key slots per batch in the out-tile (16*144*4B = 9216B)

// ws layout:
//   [0,131072)       w3t  bf16 (1024x64)       w3t[col*64+k]
//   [131072,139264)  w2t  bf16 (64x64)         w2t[col*64+k]
//   [139264,4333568) featT bf16 (32*4096*16)   featT[((c*4096+src)*16)+b]
#define WS_W3T_OFF    0
#define WS_W2T_OFF    131072
#define WS_FEATT_OFF  139264
#define WS_NEED       4333568

__global__ void qc_zero_kernel(float* __restrict__ out, int n4) {
    int i = blockIdx.x * blockDim.x + threadIdx.x;
    if (i < n4) ((float4*)out)[i] = make_float4(0.f, 0.f, 0.f, 0.f);
}

__global__ void qc_prep_kernel(const float* __restrict__ w3, const float* __restrict__ w2,
                               __bf16* __restrict__ w3t, __bf16* __restrict__ w2t) {
    int gid = blockIdx.x * blockDim.x + threadIdx.x;
    if (gid < 65536) {
        int k = gid & 63, col = gid >> 6;
        w3t[gid] = (__bf16)w3[k * 1024 + col];
    } else {
        int j = gid - 65536;
        int k = j & 63, col = j >> 6;
        w2t[j] = (__bf16)w2[k * 64 + col];
    }
}

// Fused prep: heavy blocks first (featT 0..511, w3t 512..527, w2t 528),
// trivial zero blocks last. w3t transpose via LDS tile (coalesced both ways).
__global__ void qc_prep2_kernel(const float* __restrict__ w3, const float* __restrict__ w2,
                                const float* __restrict__ feat,
                                float* __restrict__ out,
                                __bf16* __restrict__ w3t, __bf16* __restrict__ w2t,
                                __bf16* __restrict__ featT) {
    int bid = blockIdx.x, tid = threadIdx.x;
    if (bid < 512) {
        int c    = bid >> 4;                         // 0..31
        int src  = (bid & 15) * 256 + tid;           // 0..4095
        bf16x16 v;
        #pragma unroll
        for (int b = 0; b < 16; ++b)
            v[b] = (__bf16)feat[(b * 32 + c) * N_IN + src];
        __bf16* p = &featT[((size_t)c * N_IN + src) * 16];
        *(bf16x8*)p       = *(bf16x8*)&v;
        *(bf16x8*)(p + 8) = *((bf16x8*)&v + 1);
    } else if (bid < 528) {
        __shared__ float tile[64][65];
        const int colbase = (bid - 512) * 64;
        #pragma unroll
        for (int it = 0; it < 16; ++it) {
            int k = it * 4 + (tid >> 6);
            int c = tid & 63;
            tile[k][c] = w3[k * 1024 + colbase + c];
        }
        __syncthreads();
        int cc = tid >> 2;
        int k0 = (tid & 3) * 16;
        bf16x8 o0, o1;
        #pragma unroll
        for (int z = 0; z < 8; ++z) {
            o0[z] = (__bf16)tile[k0 + z][cc];
            o1[z] = (__bf16)tile[k0 + 8 + z][cc];
        }
        __bf16* wp = &w3t[(colbase + cc) * 64 + k0];
        *(bf16x8*)wp       = o0;
        *(bf16x8*)(wp + 8) = o1;
    } else if (bid == 528) {
        #pragma unroll
        for (int z = 0; z < 16; ++z) {
            int j = tid * 16 + z;
            w2t[j] = (__bf16)w2[(j & 63) * 64 + (j >> 6)];
        }
    } else {
        int i = (bid - 529) * 256 + tid;
        ((float4*)out)[i] = make_float4(0.f, 0.f, 0.f, 0.f);
    }
}

// ---------------------------------------------------------------------------
// Fused 32-row kernel, V6 = R3 structure (67.5us proven) with a two-level
// scatter replacing the per-thread global atomics:
//   E1: run-merged accumulation into an LDS out-tile tile[16][TILE_K]
//       (overlaying dead h1b/h2b; keys of a block form a dense range NK<=~70,
//        TILE_K=144 bound; LDS float atomics).
//   E2: after one barrier, coalesced writeback: interior keys (provably all
//       items inside this block: 0<idx<NK-1) are PLAIN stores; only the <=4
//       boundary keys per block use global atomicAdd. Global atomics drop
//       ~1.2M -> ~90K; WRITE_SIZE amplification (26MB vs 2MB out) collapses.
// ---------------------------------------------------------------------------
__global__ __launch_bounds__(512, 2)
void qc_fused32_kernel(const __bf16* __restrict__ featT,
                       const float* __restrict__ w1,
                       const float* __restrict__ locs,
                       const int*   __restrict__ eidx,
                       const __bf16* __restrict__ w2t,
                       const __bf16* __restrict__ w3t,
                       float* __restrict__ out,
                       int E)
{
    __shared__ __align__(16) unsigned char region1[41472]; // gb/ftv/vals
    __shared__ __align__(16) unsigned char region2[9216];  // h1b/h2b -> out-tile
    __shared__ unsigned short seg_s[32 * SEG_STR];         // 2176 B
    // total 52864 B -> 3 blocks/CU

    __bf16* gb   = (__bf16*)region1;   // [b][tl] stride GSTR2   (33536 B)
    __bf16* ftv  = (__bf16*)region1;   // [n:32][jslot:16*40+8]  (41472 B)
    __bf16* vals = (__bf16*)region1;   // [b][w*40+j] stride VSTR2 (41216 B)

    __bf16* h1b  = (__bf16*)region2;            // 32*72*2 = 4608 B
    __bf16* h2b  = (__bf16*)(region2 + 9216/2); // 4608 B
    float*  tile = (float*)region2;             // 16*TILE_K floats = 9216 B

    const int tid  = threadIdx.x;
    const int lane = tid & 63;
    const int wv   = tid >> 6;      // 0..7
    const int ml   = lane & 15;
    const int q    = lane >> 4;
    const int n0   = blockIdx.x * 32;
    const int t0   = n0 * 32;
    const int ch0  = t0 / E;
    const int m0   = t0 - ch0 * E;     // block spans <1024 t's -> at most one wrap

    // ---- Gather (wave-owned slots) + top-of-block weight loads ----
    const int tlb = wv * 128 + lane;
    bf16x16 gvv[2];
    int sgv[2];
    #pragma unroll
    for (int h = 0; h < 2; ++h) {
        int tl = tlb + h * 64;
        int mm = m0 + tl;
        int cc = ch0 + (mm >= E);
        if (mm >= E) mm -= E;
        int2 p = ((const int2*)eidx)[mm];      // .x = seg, .y = src
        sgv[h] = p.x;
        int ccc = cc < 32 ? cc : 31;
        bf16x16 g = *(const bf16x16*)&featT[((size_t)ccc * N_IN + p.y) * 16];
        if (cc >= 32) {
            #pragma unroll
            for (int z = 0; z < 16; ++z) g[z] = (__bf16)0.f;
        }
        gvv[h] = g;
    }
    // Phase-B weights, issued early so L2 latency hides under Phase A
    const int rg = (wv >> 2) * 16;
    const int cw = (wv & 3) * 16;
    const bf16x8 bw0 = *(const bf16x8*)&w2t[(cw + ml) * 64 + q * 8];
    const bf16x8 bw1 = *(const bf16x8*)&w2t[(cw + ml) * 64 + 32 + q * 8];

    // ---- Phase A: h1 = sin(loc @ W1) ----
    {
        const int r  = tid >> 4;               // 0..31
        const int j0 = (tid & 15) * 4;
        float lx = 0.f, ly = 0.f;
        int n = n0 + r;
        if (n < E) { lx = locs[n * 2]; ly = locs[n * 2 + 1]; }
        float4 wa = *(const float4*)&w1[j0];
        float4 wb = *(const float4*)&w1[64 + j0];
        __bf16* hp = &h1b[r * H1_STR + j0];
        hp[0] = (__bf16)__sinf(lx * wa.x + ly * wb.x);
        hp[1] = (__bf16)__sinf(lx * wa.y + ly * wb.y);
        hp[2] = (__bf16)__sinf(lx * wa.z + ly * wb.z);
        hp[3] = (__bf16)__sinf(lx * wa.w + ly * wb.w);
    }
    __syncthreads();   // S1

    // ---- Phase B: h2 = sin(h1 @ W2) ----
    {
        bf16x8 a0 = *(const bf16x8*)&h1b[(rg + ml) * H1_STR + q * 8];
        bf16x8 a1 = *(const bf16x8*)&h1b[(rg + ml) * H1_STR + 32 + q * 8];
        f32x4 c = {0.f, 0.f, 0.f, 0.f};
        c = __builtin_amdgcn_mfma_f32_16x16x32_bf16(a0, bw0, c, 0, 0, 0);
        c = __builtin_amdgcn_mfma_f32_16x16x32_bf16(a1, bw1, c, 0, 0, 0);
        #pragma unroll
        for (int g_ = 0; g_ < 4; ++g_)
            h2b[(rg + q * 4 + g_) * H2_STR + cw + ml] = (__bf16)__sinf(c[g_]);
    }

    // ---- Park own gather + seg; preload einsum A-frags (same-wave RAW) ----
    #pragma unroll
    for (int b = 0; b < 16; ++b) {
        gb[b * GSTR2 + tlb]      = gvv[0][b];
        gb[b * GSTR2 + tlb + 64] = gvv[1][b];
    }
    seg_s[(tlb >> 5) * SEG_STR + (tlb & 31)] = (unsigned short)sgv[0];
    {
        int tl1 = tlb + 64;
        seg_s[(tl1 >> 5) * SEG_STR + (tl1 & 31)] = (unsigned short)sgv[1];
    }
    bf16x8 ag[4];
    #pragma unroll
    for (int rr = 0; rr < 4; ++rr)
        ag[rr] = *(const bf16x8*)&gb[ml * GSTR2 + (wv * 4 + rr) * 32 + q * 8];
    __syncthreads();   // S2: h2b ready; ag preloads done; region becomes ftv

    bf16x8 ha00 = *(const bf16x8*)&h2b[ml * H2_STR + q * 8];
    bf16x8 ha01 = *(const bf16x8*)&h2b[ml * H2_STR + 32 + q * 8];
    bf16x8 ha10 = *(const bf16x8*)&h2b[(16 + ml) * H2_STR + q * 8];
    bf16x8 ha11 = *(const bf16x8*)&h2b[(16 + ml) * H2_STR + 32 + q * 8];

    f32x4 c0[4], c1[4];

    // ---- C-pass0: filt cols j<16, acc in regs, 8x b64 writes ----
    {
        f32x4 accA[4], accB[4];
        #pragma unroll
        for (int tt = 0; tt < 4; ++tt) {
            int i_  = wv * 4 + tt;
            int col = i_ * 32 + ml;            // j = ml < 16
            const __bf16* wp = &w3t[col * 64 + q * 8];
            bf16x8 b0 = *(const bf16x8*)wp;
            bf16x8 b1 = *(const bf16x8*)(wp + 32);
            f32x4 cA = {0.f, 0.f, 0.f, 0.f};
            f32x4 cB = {0.f, 0.f, 0.f, 0.f};
            cA = __builtin_amdgcn_mfma_f32_16x16x32_bf16(ha00, b0, cA, 0, 0, 0);
            cA = __builtin_amdgcn_mfma_f32_16x16x32_bf16(ha01, b1, cA, 0, 0, 0);
            cB = __builtin_amdgcn_mfma_f32_16x16x32_bf16(ha10, b0, cB, 0, 0, 0);
            cB = __builtin_amdgcn_mfma_f32_16x16x32_bf16(ha11, b1, cB, 0, 0, 0);
            accA[tt] = cA; accB[tt] = cB;
        }
        #pragma unroll
        for (int g_ = 0; g_ < 4; ++g_) {
            bf16x4 pa, pb;
            #pragma unroll
            for (int tt = 0; tt < 4; ++tt) {
                pa[tt] = (__bf16)accA[tt][g_];
                pb[tt] = (__bf16)accB[tt][g_];
            }
            *(bf16x4*)&ftv[(q * 4 + g_) * FTH_NSTR + ml * FT_JSTR + wv * 4]        = pa;
            *(bf16x4*)&ftv[(16 + q * 4 + g_) * FTH_NSTR + ml * FT_JSTR + wv * 4]   = pb;
        }
    }
    __syncthreads();   // S3 -- all waves past their h1b/h2b reads: tile may be zeroed

    // ---- zero the out-tile (overlays h1b/h2b, both dead now) ----
    #pragma unroll
    for (int z = 0; z < 5; ++z) {
        int i = tid + z * 512;
        if (i < 16 * TILE_K) tile[i] = 0.f;
    }

    // ---- D-pass0: vals j<16; wave handles its own rows wv*4..+4 ----
    {
        bf16x8 f[4];
        #pragma unroll
        for (int rr = 0; rr < 4; ++rr)
            f[rr] = *(const bf16x8*)&ftv[(wv * 4 + rr) * FTH_NSTR + ml * FT_JSTR + q * 8];
        #pragma unroll
        for (int rr = 0; rr < 4; ++rr) {
            f32x4 z = {0.f, 0.f, 0.f, 0.f};
            c0[rr] = __builtin_amdgcn_mfma_f32_16x16x32_bf16(ag[rr], f[rr], z, 0, 0, 0);
        }
    }
    __syncthreads();   // S4 (ftv reads done)

    // ---- C-pass1: filt cols j>=16 (overwrite ftv) ----
    {
        f32x4 accA[4], accB[4];
        #pragma unroll
        for (int tt = 0; tt < 4; ++tt) {
            int i_  = wv * 4 + tt;
            int col = i_ * 32 + 16 + ml;       // j = 16 + ml
            const __bf16* wp = &w3t[col * 64 + q * 8];
            bf16x8 b0 = *(const bf16x8*)wp;
            bf16x8 b1 = *(const bf16x8*)(wp + 32);
            f32x4 cA = {0.f, 0.f, 0.f, 0.f};
            f32x4 cB = {0.f, 0.f, 0.f, 0.f};
            cA = __builtin_amdgcn_mfma_f32_16x16x32_bf16(ha00, b0, cA, 0, 0, 0);
            cA = __builtin_amdgcn_mfma_f32_16x16x32_bf16(ha01, b1, cA, 0, 0, 0);
            cB = __builtin_amdgcn_mfma_f32_16x16x32_bf16(ha10, b0, cB, 0, 0, 0);
            cB = __builtin_amdgcn_mfma_f32_16x16x32_bf16(ha11, b1, cB, 0, 0, 0);
            accA[tt] = cA; accB[tt] = cB;
        }
        #pragma unroll
        for (int g_ = 0; g_ < 4; ++g_) {
            bf16x4 pa, pb;
            #pragma unroll
            for (int tt = 0; tt < 4; ++tt) {
                pa[tt] = (__bf16)accA[tt][g_];
                pb[tt] = (__bf16)accB[tt][g_];
            }
            *(bf16x4*)&ftv[(q * 4 + g_) * FTH_NSTR + ml * FT_JSTR + wv * 4]        = pa;
            *(bf16x4*)&ftv[(16 + q * 4 + g_) * FTH_NSTR + ml * FT_JSTR + wv * 4]   = pb;
        }
    }
    __syncthreads();   // S5

    // ---- D-pass1 loads, then region becomes vals ----
    bf16x8 f1[4];
    #pragma unroll
    for (int rr = 0; rr < 4; ++rr)
        f1[rr] = *(const bf16x8*)&ftv[(wv * 4 + rr) * FTH_NSTR + ml * FT_JSTR + q * 8];
    __syncthreads();   // S6 (ftv dead; region becomes vals)
    #pragma unroll
    for (int rr = 0; rr < 4; ++rr) {
        f32x4 z = {0.f, 0.f, 0.f, 0.f};
        c1[rr] = __builtin_amdgcn_mfma_f32_16x16x32_bf16(ag[rr], f1[rr], z, 0, 0, 0);
    }
    #pragma unroll
    for (int rr = 0; rr < 4; ++rr) {
        int r = wv * 4 + rr;                   // r == window index w
        __bf16* vp = &vals[r * FT_JSTR];       // per-w stride 40
        #pragma unroll
        for (int g_ = 0; g_ < 4; ++g_) {
            int b = q * 4 + g_;
            vp[b * VSTR2 + ml]      = (__bf16)c0[rr][g_];
            vp[b * VSTR2 + 16 + ml] = (__bf16)c1[rr][g_];
        }
    }
    __syncthreads();   // S7

    // ---- Phase E: two-level scatter ----
    {
        const int be = tid >> 5;              // 0..15
        const int w  = tid & 31;
        const __bf16* vp = &vals[be * VSTR2 + w * FT_JSTR];
        bf16x8 v0 = *(const bf16x8*)(vp);
        bf16x8 v1 = *(const bf16x8*)(vp + 8);
        bf16x8 v2 = *(const bf16x8*)(vp + 16);
        bf16x8 v3 = *(const bf16x8*)(vp + 24);
        float vv[32];
        #pragma unroll
        for (int j = 0; j < 8; ++j) {
            vv[j]      = (float)v0[j];
            vv[8 + j]  = (float)v1[j];
            vv[16 + j] = (float)v2[j];
            vv[24 + j] = (float)v3[j];
        }

        // block-uniform dense key range: idx = seg-seg0 (part1) | OFF+seg (part2)
        const int seg0 = (int)seg_s[0];
        const int segL = (int)seg_s[31 * SEG_STR + 31];
        const int tlw  = E - m0;               // wrap position (>=1)
        const bool wrap = (tlw < 1024);
        int OFF = 0, NK;
        if (wrap) {
            int tw = tlw - 1;                  // last item of part 1
            OFF = (int)seg_s[(tw >> 5) * SEG_STR + (tw & 31)] - seg0 + 1;
            NK  = OFF + segL + 1;
        } else {
            NK = segL - seg0 + 1;
        }

        int mwin = m0 + (w << 5);
        int cb   = ch0;
        if (mwin >= E) { mwin -= E; ++cb; }
        int jcross = E - mwin;                 // wrap inside window iff < 32

        if (NK <= TILE_K) {
            // E1: run-merged accumulation into LDS tile
            const int NEG = -0x40000000;
            int io0 = (cb < 32) ? ((cb == ch0) ? -seg0 : OFF) : NEG;
            int io1 = (cb + 1 < 32) ? OFF : NEG;   // window crossing implies cb==ch0
            int key_prev = -1;
            float acc = 0.f;
            #pragma unroll
            for (int j = 0; j < 32; ++j) {
                int io = (j < jcross) ? io0 : io1;
                if (io != NEG) {
                    int key = io + (int)seg_s[w * SEG_STR + j];
                    if (key != key_prev) {
                        if (key_prev >= 0) atomicAdd(&tile[be * TILE_K + key_prev], acc);
                        key_prev = key;
                        acc = vv[j];
                    } else {
                        acc += vv[j];
                    }
                }
            }
            if (key_prev >= 0) atomicAdd(&tile[be * TILE_K + key_prev], acc);

            __syncthreads();   // S8 (uniform branch: NK is block-uniform)

            // E2: coalesced writeback; interior keys are exclusive -> plain store
            for (int bb = 0; bb < 16; ++bb) {
                for (int i = tid; i < NK; i += 512) {
                    int cbx, sg;
                    if (wrap && i >= OFF) { cbx = ch0 + 1; sg = i - OFF; }
                    else                  { cbx = ch0;     sg = seg0 + i; }
                    if (cbx < 32) {
                        float v = tile[bb * TILE_K + i];
                        int o = (bb << 15) | (cbx << 10) | sg;
                        bool bnd = (i == 0) || (i == NK - 1) ||
                                   (wrap && (i == OFF - 1 || i == OFF));
                        if (bnd) atomicAdd(&out[o], v);
                        else     out[o] = v;
                    }
                }
            }
        } else {
            // fallback (never expected: NK <= ~70): direct global atomics (R3 path)
            int base0 = (cb < 32)     ? ((be << 15) | (cb << 10))       : -1;
            int base1 = (cb + 1 < 32) ? ((be << 15) | ((cb + 1) << 10)) : -1;
            int key_prev = -1;
            float acc = 0.f;
            #pragma unroll
            for (int j = 0; j < 32; ++j) {
                int basej = (j < jcross) ? base0 : base1;
                if (basej >= 0) {
                    int key = basej + (int)seg_s[w * SEG_STR + j];
                    if (key != key_prev) {
                        if (key_prev >= 0) atomicAdd(&out[key_prev], acc);
                        key_prev = key;
                        acc = vv[j];
                    } else {
                        acc += vv[j];
                    }
                }
            }
            if (key_prev >= 0) atomicAdd(&out[key_prev], acc);
        }
    }
}

// ---------------------------------------------------------------------------
// Fallback: round-1 fused kernel (used only if ws too small)
// ---------------------------------------------------------------------------
__global__ __launch_bounds__(256, 2)
void qc_main_kernel(const float* __restrict__ feat,
                    const float* __restrict__ w1,
                    const float* __restrict__ w2,
                    const float* __restrict__ locs,
                    const int*   __restrict__ eidx,
                    const __bf16* __restrict__ w3t,
                    float* __restrict__ out,
                    int E)
{
    __shared__ __align__(16) __bf16 h1b[ROWS * H1_STR];
    __shared__ __align__(16) __bf16 h2b[ROWS * H2_STR];
    __shared__ __align__(16) __bf16 ftv[ROWS * FB_FT_NSTR];
    __shared__ __align__(16) __bf16 gb [BATCH * G_STR];
    __shared__ unsigned short seg_s[512];
    __shared__ unsigned short src_s[512];

    const int tid = threadIdx.x;
    const int n0  = blockIdx.x * ROWS;
    const int t0  = n0 * 32;
    const int ch0 = t0 / E;
    const int m0  = t0 - ch0 * E;

    {
        const int r  = tid >> 4;
        const int j0 = (tid & 15) * 4;
        float lx = 0.f, ly = 0.f;
        int n = n0 + r;
        if (n < E) { lx = locs[n * 2]; ly = locs[n * 2 + 1]; }
        float4 wa = *(const float4*)&w1[j0];
        float4 wb = *(const float4*)&w1[64 + j0];
        __bf16* h = &h1b[r * H1_STR + j0];
        h[0] = (__bf16)__sinf(lx * wa.x + ly * wb.x);
        h[1] = (__bf16)__sinf(lx * wa.y + ly * wb.y);
        h[2] = (__bf16)__sinf(lx * wa.z + ly * wb.z);
        h[3] = (__bf16)__sinf(lx * wa.w + ly * wb.w);
    }
    for (int tl = tid; tl < 512; tl += 256) {
        int mm = m0 + tl; if (mm >= E) mm -= E;
        seg_s[tl] = (unsigned short)eidx[mm * 2];
        src_s[tl] = (unsigned short)eidx[mm * 2 + 1];
    }
    __syncthreads();

    {
        const int r  = tid >> 4;
        const int j0 = (tid & 15) * 4;
        float a0 = 0.f, a1 = 0.f, a2 = 0.f, a3 = 0.f;
        const __bf16* h1r = &h1b[r * H1_STR];
        #pragma unroll 8
        for (int k = 0; k < 64; ++k) {
            float h = (float)h1r[k];
            float4 w = *(const float4*)&w2[k * 64 + j0];
            a0 += h * w.x; a1 += h * w.y; a2 += h * w.z; a3 += h * w.w;
        }
        __bf16* h = &h2b[r * H2_STR + j0];
        h[0] = (__bf16)__sinf(a0);
        h[1] = (__bf16)__sinf(a1);
        h[2] = (__bf16)__sinf(a2);
        h[3] = (__bf16)__sinf(a3);
    }
    #pragma unroll 4
    for (int it = 0; it < 32; ++it) {
        int idx = it * 256 + tid;
        int b   = idx >> 9;
        int tl  = idx & 511;
        int mm  = m0 + tl;
        int cc  = ch0 + (mm >= E);
        if (mm >= E) mm -= E;
        float v = 0.f;
        if (cc < 32) v = feat[(b * 32 + cc) * N_IN + (int)src_s[tl]];
        gb[b * G_STR + tl] = (__bf16)v;
    }
    __syncthreads();

    const int lane = tid & 63;
    const int wv   = tid >> 6;
    const int ml   = lane & 15;
    const int q    = lane >> 4;

    {
        bf16x8 a0 = *(const bf16x8*)&h2b[ml * H2_STR + q * 8];
        bf16x8 a1 = *(const bf16x8*)&h2b[ml * H2_STR + 32 + q * 8];
        #pragma unroll
        for (int t = 0; t < 16; ++t) {
            int col = wv * 256 + t * 16 + ml;
            const __bf16* wp = &w3t[col * 64 + q * 8];
            bf16x8 b0 = *(const bf16x8*)wp;
            bf16x8 b1 = *(const bf16x8*)(wp + 32);
            f32x4 c = {0.f, 0.f, 0.f, 0.f};
            c = __builtin_amdgcn_mfma_f32_16x16x32_bf16(a0, b0, c, 0, 0, 0);
            c = __builtin_amdgcn_mfma_f32_16x16x32_bf16(a1, b1, c, 0, 0, 0);
            int i_ = col >> 5, j_ = col & 31;
            __bf16* fp = &ftv[j_ * FT_JSTR + i_];
            fp[(q * 4 + 0) * FB_FT_NSTR] = (__bf16)c[0];
            fp[(q * 4 + 1) * FB_FT_NSTR] = (__bf16)c[1];
            fp[(q * 4 + 2) * FB_FT_NSTR] = (__bf16)c[2];
            fp[(q * 4 + 3) * FB_FT_NSTR] = (__bf16)c[3];
        }
    }
    __syncthreads();

    {
        bf16x8 ag[4], f0[4], f1[4];
        #pragma unroll
        for (int rr = 0; rr < 4; ++rr) {
            int r = wv * 4 + rr;
            ag[rr] = *(const bf16x8*)&gb[ml * G_STR + r * 32 + q * 8];
            f0[rr] = *(const bf16x8*)&ftv[r * FB_FT_NSTR + ml        * FT_JSTR + q * 8];
            f1[rr] = *(const bf16x8*)&ftv[r * FB_FT_NSTR + (16 + ml) * FT_JSTR + q * 8];
        }
        __syncthreads();
        __bf16* valsb = ftv;
        #pragma unroll
        for (int rr = 0; rr < 4; ++rr) {
            int r = wv * 4 + rr;
            f32x4 c0 = {0.f, 0.f, 0.f, 0.f};
            f32x4 c1 = {0.f, 0.f, 0.f, 0.f};
            c0 = __builtin_amdgcn_mfma_f32_16x16x32_bf16(ag[rr], f0[rr], c0, 0, 0, 0);
            c1 = __builtin_amdgcn_mfma_f32_16x16x32_bf16(ag[rr], f1[rr], c1, 0, 0, 0);
            __bf16* vp = &valsb[r * 32];
            #pragma unroll
            for (int g_ = 0; g_ < 4; ++g_) {
                int b = q * 4 + g_;
                vp[b * V_STR + ml]      = (__bf16)c0[g_];
                vp[b * V_STR + 16 + ml] = (__bf16)c1[g_];
            }
        }
    }
    __syncthreads();

    {
        const __bf16* valsb = ftv;
        const int b = tid >> 4;
        const int r = tid & 15;
        const __bf16* vp = &valsb[b * V_STR + r * 32];
        bf16x8 v0 = *(const bf16x8*)(vp);
        bf16x8 v1 = *(const bf16x8*)(vp + 8);
        bf16x8 v2 = *(const bf16x8*)(vp + 16);
        bf16x8 v3 = *(const bf16x8*)(vp + 24);
        float vv[32];
        #pragma unroll
        for (int j = 0; j < 8; ++j) {
            vv[j]      = (float)v0[j];
            vv[8 + j]  = (float)v1[j];
            vv[16 + j] = (float)v2[j];
            vv[24 + j] = (float)v3[j];
        }
        const int tl0 = r * 32;
        int key_prev = -1;
        float acc = 0.f;
        #pragma unroll
        for (int j = 0; j < 32; ++j) {
            int mm = m0 + tl0 + j;
            int cc = ch0 + (mm >= E);
            if (mm >= E) mm -= E;
            if (cc < 32) {
                int o   = (int)seg_s[tl0 + j];
                int key = ((b * 32 + cc) << 10) | o;
                if (key != key_prev) {
                    if (key_prev >= 0) atomicAdd(&out[key_prev], acc);
                    key_prev = key;
                    acc = vv[j];
                } else {
                    acc += vv[j];
                }
            }
        }
        if (key_prev >= 0) atomicAdd(&out[key_prev], acc);
    }
}

extern "C" void kernel_launch(void* const* d_in, const int* in_sizes, int n_in,
                              void* d_out, int out_size, void* d_ws, size_t ws_size,
                              hipStream_t stream)
{
    (void)n_in;
    const float* feat = (const float*)d_in[0];
    const float* w1   = (const float*)d_in[1];
    const float* w2   = (const float*)d_in[2];
    const float* w3   = (const float*)d_in[3];
    const float* locs = (const float*)d_in[4];
    const int*   eidx = (const int*)d_in[5];
    float* out  = (float*)d_out;

    const int E = in_sizes[4] / 2;
    if (E <= 0) return;

    __bf16* w3t   = (__bf16*)((char*)d_ws + WS_W3T_OFF);
    __bf16* w2t   = (__bf16*)((char*)d_ws + WS_W2T_OFF);
    __bf16* featT = (__bf16*)((char*)d_ws + WS_FEATT_OFF);

    if (ws_size >= (size_t)WS_NEED) {
        int nblocks = (E + 31) / 32;
        qc_prep2_kernel<<<1041, 256, 0, stream>>>(w3, w2, feat, out, w3t, w2t, featT);
        qc_fused32_kernel<<<nblocks, 512, 0, stream>>>(featT, w1, locs, eidx, w2t, w3t, out, E);
    } else {
        int n4 = out_size / 4;
        int nblocks = (E + ROWS - 1) / ROWS;
        qc_zero_kernel<<<(n4 + 255) / 256, 256, 0, stream>>>(out, n4);
        qc_prep_kernel<<<272, 256, 0, stream>>>(w3, w2, w3t, w2t);
        qc_main_kernel<<<nblocks, 256, 0, stream>>>(feat, w1, w2, locs, eidx, w3t, out, E);
    }
}

// Round 6
// 121.407 us; speedup vs baseline: 1.1556x; 1.0482x over previous
//
#include <hip/hip_runtime.h>
#include <hip/hip_bf16.h>

typedef __bf16 bf16x4  __attribute__((ext_vector_type(4)));
typedef __bf16 bf16x8  __attribute__((ext_vector_type(8)));
typedef __bf16 bf16x16 __attribute__((ext_vector_type(16)));
typedef float  f32x4   __attribute__((ext_vector_type(4)));

#define N_IN   4096
#define N_OUT  1024
#define BATCH  16
#define ROWS   16     // fallback kernel tile

// LDS strides in __bf16 elements
#define H1_STR   72
#define H2_STR   72
#define FT_JSTR  40     // i-stride inside a j-slot row
#define FTH_NSTR 648    // per-n stride (16 j * 40 + 8 pad)
#define G_STR    520    // fallback
#define V_STR    520    // fallback
#define GSTR2    1048   // gb stride (1024 + 24)
#define FB_FT_NSTR 1288 // fallback
#define SEG_STR  34     // seg_s per-window stride (17-word stride -> bank-spread)
#define WSLAB    2592   // per-wave vals slab = 4 * FTH_NSTR (wave-private after S5)
#define TILE_K   132    // dense key slots per batch (132%32=4 -> E1 lanes on 8 banks)

// ws layout:
//   [0,131072)       w3t  bf16 (1024x64)       w3t[col*64+k]
//   [131072,139264)  w2t  bf16 (64x64)         w2t[col*64+k]
//   [139264,4333568) featT bf16 (32*4096*16)   featT[((c*4096+src)*16)+b]
#define WS_W3T_OFF    0
#define WS_W2T_OFF    131072
#define WS_FEATT_OFF  139264
#define WS_NEED       4333568

__global__ void qc_zero_kernel(float* __restrict__ out, int n4) {
    int i = blockIdx.x * blockDim.x + threadIdx.x;
    if (i < n4) ((float4*)out)[i] = make_float4(0.f, 0.f, 0.f, 0.f);
}

__global__ void qc_prep_kernel(const float* __restrict__ w3, const float* __restrict__ w2,
                               __bf16* __restrict__ w3t, __bf16* __restrict__ w2t) {
    int gid = blockIdx.x * blockDim.x + threadIdx.x;
    if (gid < 65536) {
        int k = gid & 63, col = gid >> 6;
        w3t[gid] = (__bf16)w3[k * 1024 + col];
    } else {
        int j = gid - 65536;
        int k = j & 63, col = j >> 6;
        w2t[j] = (__bf16)w2[k * 64 + col];
    }
}

// Fused prep: heavy blocks first (featT 0..511, w3t 512..527, w2t 528),
// trivial zero blocks last. w3t transpose via LDS tile (coalesced both ways).
__global__ void qc_prep2_kernel(const float* __restrict__ w3, const float* __restrict__ w2,
                                const float* __restrict__ feat,
                                float* __restrict__ out,
                                __bf16* __restrict__ w3t, __bf16* __restrict__ w2t,
                                __bf16* __restrict__ featT) {
    int bid = blockIdx.x, tid = threadIdx.x;
    if (bid < 512) {
        int c    = bid >> 4;                         // 0..31
        int src  = (bid & 15) * 256 + tid;           // 0..4095
        bf16x16 v;
        #pragma unroll
        for (int b = 0; b < 16; ++b)
            v[b] = (__bf16)feat[(b * 32 + c) * N_IN + src];
        __bf16* p = &featT[((size_t)c * N_IN + src) * 16];
        *(bf16x8*)p       = *(bf16x8*)&v;
        *(bf16x8*)(p + 8) = *((bf16x8*)&v + 1);
    } else if (bid < 528) {
        __shared__ float tile[64][65];
        const int colbase = (bid - 512) * 64;
        #pragma unroll
        for (int it = 0; it < 16; ++it) {
            int k = it * 4 + (tid >> 6);
            int c = tid & 63;
            tile[k][c] = w3[k * 1024 + colbase + c];
        }
        __syncthreads();
        int cc = tid >> 2;
        int k0 = (tid & 3) * 16;
        bf16x8 o0, o1;
        #pragma unroll
        for (int z = 0; z < 8; ++z) {
            o0[z] = (__bf16)tile[k0 + z][cc];
            o1[z] = (__bf16)tile[k0 + 8 + z][cc];
        }
        __bf16* wp = &w3t[(colbase + cc) * 64 + k0];
        *(bf16x8*)wp       = o0;
        *(bf16x8*)(wp + 8) = o1;
    } else if (bid == 528) {
        #pragma unroll
        for (int z = 0; z < 16; ++z) {
            int j = tid * 16 + z;
            w2t[j] = (__bf16)w2[(j & 63) * 64 + (j >> 6)];
        }
    } else {
        int i = (bid - 529) * 256 + tid;
        ((float4*)out)[i] = make_float4(0.f, 0.f, 0.f, 0.f);
    }
}

// ---------------------------------------------------------------------------
// Fused 32-row kernel, V7 = V6 (LDS-tile two-level scatter, 61us proven) +
// barrier diet (8 -> 6):
//   After S5 the ftv region partitions into 8 wave-private 5184B slabs
//   (wave wv's D1 rows [4wv,4wv+4) == its vals slab == its E1 read range;
//   seg windows [4wv,4wv+4) were written by wave wv itself). D-pass1, vals
//   writes, and the E1 run-merge into the LDS tile are all same-wave ordered
//   -> S6/S7 deleted. E1's tile atomics are LDS (no HBM mapping hazard --
//   that was R4's regression, now structurally gone). TILE_K 144->132 so
//   E1's 16 batch-lanes land on 8 banks not 2. E2 writeback flattened to
//   one key per thread (was 16 divergent serial iterations).
// ---------------------------------------------------------------------------
__global__ __launch_bounds__(512, 2)
void qc_fused32_kernel(const __bf16* __restrict__ featT,
                       const float* __restrict__ w1,
                       const float* __restrict__ locs,
                       const int*   __restrict__ eidx,
                       const __bf16* __restrict__ w2t,
                       const __bf16* __restrict__ w3t,
                       float* __restrict__ out,
                       int E)
{
    __shared__ __align__(16) unsigned char region1[41472]; // gb/ftv/vals
    __shared__ __align__(16) unsigned char region2[9216];  // h1b/h2b -> out-tile
    __shared__ unsigned short seg_s[32 * SEG_STR];         // 2176 B

    __bf16* gb   = (__bf16*)region1;   // [b][tl] stride GSTR2   (33536 B)
    __bf16* ftv  = (__bf16*)region1;   // [n:32][jslot:16*40+8]  (41472 B)
    __bf16* vals = (__bf16*)region1;   // 8 wave-private slabs of WSLAB shorts

    __bf16* h1b  = (__bf16*)region2;            // 4608 B
    __bf16* h2b  = (__bf16*)(region2 + 9216/2); // 4608 B
    float*  tile = (float*)region2;             // 16*TILE_K floats = 8448 B

    const int tid  = threadIdx.x;
    const int lane = tid & 63;
    const int wv   = tid >> 6;      // 0..7
    const int ml   = lane & 15;
    const int q    = lane >> 4;
    const int n0   = blockIdx.x * 32;
    const int t0   = n0 * 32;
    const int ch0  = t0 / E;
    const int m0   = t0 - ch0 * E;     // block spans <1024 t's -> at most one wrap

    // ---- Gather (wave-owned slots) + top-of-block weight loads ----
    const int tlb = wv * 128 + lane;
    bf16x16 gvv[2];
    int sgv[2];
    #pragma unroll
    for (int h = 0; h < 2; ++h) {
        int tl = tlb + h * 64;
        int mm = m0 + tl;
        int cc = ch0 + (mm >= E);
        if (mm >= E) mm -= E;
        int2 p = ((const int2*)eidx)[mm];      // .x = seg, .y = src
        sgv[h] = p.x;
        int ccc = cc < 32 ? cc : 31;
        bf16x16 g = *(const bf16x16*)&featT[((size_t)ccc * N_IN + p.y) * 16];
        if (cc >= 32) {
            #pragma unroll
            for (int z = 0; z < 16; ++z) g[z] = (__bf16)0.f;
        }
        gvv[h] = g;
    }
    // Phase-B weights, issued early so L2 latency hides under Phase A
    const int rg = (wv >> 2) * 16;
    const int cw = (wv & 3) * 16;
    const bf16x8 bw0 = *(const bf16x8*)&w2t[(cw + ml) * 64 + q * 8];
    const bf16x8 bw1 = *(const bf16x8*)&w2t[(cw + ml) * 64 + 32 + q * 8];

    // ---- Phase A: h1 = sin(loc @ W1) ----
    {
        const int r  = tid >> 4;               // 0..31
        const int j0 = (tid & 15) * 4;
        float lx = 0.f, ly = 0.f;
        int n = n0 + r;
        if (n < E) { lx = locs[n * 2]; ly = locs[n * 2 + 1]; }
        float4 wa = *(const float4*)&w1[j0];
        float4 wb = *(const float4*)&w1[64 + j0];
        __bf16* hp = &h1b[r * H1_STR + j0];
        hp[0] = (__bf16)__sinf(lx * wa.x + ly * wb.x);
        hp[1] = (__bf16)__sinf(lx * wa.y + ly * wb.y);
        hp[2] = (__bf16)__sinf(lx * wa.z + ly * wb.z);
        hp[3] = (__bf16)__sinf(lx * wa.w + ly * wb.w);
    }
    __syncthreads();   // S1

    // ---- Phase B: h2 = sin(h1 @ W2) ----
    {
        bf16x8 a0 = *(const bf16x8*)&h1b[(rg + ml) * H1_STR + q * 8];
        bf16x8 a1 = *(const bf16x8*)&h1b[(rg + ml) * H1_STR + 32 + q * 8];
        f32x4 c = {0.f, 0.f, 0.f, 0.f};
        c = __builtin_amdgcn_mfma_f32_16x16x32_bf16(a0, bw0, c, 0, 0, 0);
        c = __builtin_amdgcn_mfma_f32_16x16x32_bf16(a1, bw1, c, 0, 0, 0);
        #pragma unroll
        for (int g_ = 0; g_ < 4; ++g_)
            h2b[(rg + q * 4 + g_) * H2_STR + cw + ml] = (__bf16)__sinf(c[g_]);
    }

    // ---- Park own gather + seg; preload einsum A-frags (same-wave RAW) ----
    #pragma unroll
    for (int b = 0; b < 16; ++b) {
        gb[b * GSTR2 + tlb]      = gvv[0][b];
        gb[b * GSTR2 + tlb + 64] = gvv[1][b];
    }
    seg_s[(tlb >> 5) * SEG_STR + (tlb & 31)] = (unsigned short)sgv[0];
    {
        int tl1 = tlb + 64;
        seg_s[(tl1 >> 5) * SEG_STR + (tl1 & 31)] = (unsigned short)sgv[1];
    }
    bf16x8 ag[4];
    #pragma unroll
    for (int rr = 0; rr < 4; ++rr)
        ag[rr] = *(const bf16x8*)&gb[ml * GSTR2 + (wv * 4 + rr) * 32 + q * 8];
    __syncthreads();   // S2: h2b ready; ag preloads done; region becomes ftv

    bf16x8 ha00 = *(const bf16x8*)&h2b[ml * H2_STR + q * 8];
    bf16x8 ha01 = *(const bf16x8*)&h2b[ml * H2_STR + 32 + q * 8];
    bf16x8 ha10 = *(const bf16x8*)&h2b[(16 + ml) * H2_STR + q * 8];
    bf16x8 ha11 = *(const bf16x8*)&h2b[(16 + ml) * H2_STR + 32 + q * 8];

    f32x4 c0[4], c1[4];

    // ---- C-pass0: filt cols j<16, acc in regs, 8x b64 writes ----
    {
        f32x4 accA[4], accB[4];
        #pragma unroll
        for (int tt = 0; tt < 4; ++tt) {
            int i_  = wv * 4 + tt;
            int col = i_ * 32 + ml;            // j = ml < 16
            const __bf16* wp = &w3t[col * 64 + q * 8];
            bf16x8 b0 = *(const bf16x8*)wp;
            bf16x8 b1 = *(const bf16x8*)(wp + 32);
            f32x4 cA = {0.f, 0.f, 0.f, 0.f};
            f32x4 cB = {0.f, 0.f, 0.f, 0.f};
            cA = __builtin_amdgcn_mfma_f32_16x16x32_bf16(ha00, b0, cA, 0, 0, 0);
            cA = __builtin_amdgcn_mfma_f32_16x16x32_bf16(ha01, b1, cA, 0, 0, 0);
            cB = __builtin_amdgcn_mfma_f32_16x16x32_bf16(ha10, b0, cB, 0, 0, 0);
            cB = __builtin_amdgcn_mfma_f32_16x16x32_bf16(ha11, b1, cB, 0, 0, 0);
            accA[tt] = cA; accB[tt] = cB;
        }
        #pragma unroll
        for (int g_ = 0; g_ < 4; ++g_) {
            bf16x4 pa, pb;
            #pragma unroll
            for (int tt = 0; tt < 4; ++tt) {
                pa[tt] = (__bf16)accA[tt][g_];
                pb[tt] = (__bf16)accB[tt][g_];
            }
            *(bf16x4*)&ftv[(q * 4 + g_) * FTH_NSTR + ml * FT_JSTR + wv * 4]        = pa;
            *(bf16x4*)&ftv[(16 + q * 4 + g_) * FTH_NSTR + ml * FT_JSTR + wv * 4]   = pb;
        }
    }
    __syncthreads();   // S3 -- all waves past their h1b/h2b reads

    // ---- zero the out-tile (overlays h1b/h2b, both dead now) ----
    #pragma unroll
    for (int z = 0; z < 5; ++z) {
        int i = tid + z * 512;
        if (i < 16 * TILE_K) tile[i] = 0.f;
    }

    // ---- D-pass0: vals j<16; wave handles its own rows wv*4..+4 ----
    {
        bf16x8 f[4];
        #pragma unroll
        for (int rr = 0; rr < 4; ++rr)
            f[rr] = *(const bf16x8*)&ftv[(wv * 4 + rr) * FTH_NSTR + ml * FT_JSTR + q * 8];
        #pragma unroll
        for (int rr = 0; rr < 4; ++rr) {
            f32x4 z = {0.f, 0.f, 0.f, 0.f};
            c0[rr] = __builtin_amdgcn_mfma_f32_16x16x32_bf16(ag[rr], f[rr], z, 0, 0, 0);
        }
    }
    __syncthreads();   // S4 (ftv reads done; tile zero visible to all)

    // ---- C-pass1: filt cols j>=16 (overwrite ftv) ----
    {
        f32x4 accA[4], accB[4];
        #pragma unroll
        for (int tt = 0; tt < 4; ++tt) {
            int i_  = wv * 4 + tt;
            int col = i_ * 32 + 16 + ml;       // j = 16 + ml
            const __bf16* wp = &w3t[col * 64 + q * 8];
            bf16x8 b0 = *(const bf16x8*)wp;
            bf16x8 b1 = *(const bf16x8*)(wp + 32);
            f32x4 cA = {0.f, 0.f, 0.f, 0.f};
            f32x4 cB = {0.f, 0.f, 0.f, 0.f};
            cA = __builtin_amdgcn_mfma_f32_16x16x32_bf16(ha00, b0, cA, 0, 0, 0);
            cA = __builtin_amdgcn_mfma_f32_16x16x32_bf16(ha01, b1, cA, 0, 0, 0);
            cB = __builtin_amdgcn_mfma_f32_16x16x32_bf16(ha10, b0, cB, 0, 0, 0);
            cB = __builtin_amdgcn_mfma_f32_16x16x32_bf16(ha11, b1, cB, 0, 0, 0);
            accA[tt] = cA; accB[tt] = cB;
        }
        #pragma unroll
        for (int g_ = 0; g_ < 4; ++g_) {
            bf16x4 pa, pb;
            #pragma unroll
            for (int tt = 0; tt < 4; ++tt) {
                pa[tt] = (__bf16)accA[tt][g_];
                pb[tt] = (__bf16)accB[tt][g_];
            }
            *(bf16x4*)&ftv[(q * 4 + g_) * FTH_NSTR + ml * FT_JSTR + wv * 4]        = pa;
            *(bf16x4*)&ftv[(16 + q * 4 + g_) * FTH_NSTR + ml * FT_JSTR + wv * 4]   = pb;
        }
    }
    __syncthreads();   // S5 -- LAST barrier before writeback: slabs now wave-private

    // ---- block-uniform dense key range (cross-wave seg reads: written pre-S2) ----
    const int seg0 = (int)seg_s[0];
    const int segL = (int)seg_s[31 * SEG_STR + 31];
    const int tlw  = E - m0;               // wrap position (>=1)
    const bool wrap = (tlw < 1024);
    int OFF = 0, NK;
    if (wrap) {
        int tw = tlw - 1;                  // last item of part 1
        OFF = (int)seg_s[(tw >> 5) * SEG_STR + (tw & 31)] - seg0 + 1;
        NK  = OFF + segL + 1;
    } else {
        NK = segL - seg0 + 1;
    }

    // ---- D-pass1 + vals + E1: all same-wave ordered, no barriers ----
    {
        bf16x8 f1[4];
        #pragma unroll
        for (int rr = 0; rr < 4; ++rr)
            f1[rr] = *(const bf16x8*)&ftv[(wv * 4 + rr) * FTH_NSTR + ml * FT_JSTR + q * 8];
        #pragma unroll
        for (int rr = 0; rr < 4; ++rr) {
            f32x4 z = {0.f, 0.f, 0.f, 0.f};
            c1[rr] = __builtin_amdgcn_mfma_f32_16x16x32_bf16(ag[rr], f1[rr], z, 0, 0, 0);
        }
        // write own slab (same byte range the f1 reads came from; in-order WAR)
        __bf16* vslab = &vals[wv * WSLAB];
        #pragma unroll
        for (int rr = 0; rr < 4; ++rr) {
            __bf16* vp = &vslab[rr * FTH_NSTR];
            #pragma unroll
            for (int g_ = 0; g_ < 4; ++g_) {
                int b = q * 4 + g_;
                vp[b * FT_JSTR + ml]      = (__bf16)c0[rr][g_];
                vp[b * FT_JSTR + 16 + ml] = (__bf16)c1[rr][g_];
            }
        }

        // ---- E1: lane -> (b = lane&15, w = 4wv + lane>>4); own-wave data ----
        const int q2 = lane >> 4;
        const int b  = lane & 15;
        const int w  = wv * 4 + q2;
        const __bf16* vp = &vslab[q2 * FTH_NSTR + b * FT_JSTR];
        bf16x8 v0 = *(const bf16x8*)(vp);
        bf16x8 v1 = *(const bf16x8*)(vp + 8);
        bf16x8 v2 = *(const bf16x8*)(vp + 16);
        bf16x8 v3 = *(const bf16x8*)(vp + 24);
        float vv[32];
        #pragma unroll
        for (int j = 0; j < 8; ++j) {
            vv[j]      = (float)v0[j];
            vv[8 + j]  = (float)v1[j];
            vv[16 + j] = (float)v2[j];
            vv[24 + j] = (float)v3[j];
        }

        int mwin = m0 + (w << 5);
        int cb   = ch0;
        if (mwin >= E) { mwin -= E; ++cb; }
        int jcross = E - mwin;                 // wrap inside window iff < 32

        if (NK <= TILE_K) {
            const int NEG = -0x40000000;
            int io0 = (cb < 32) ? ((cb == ch0) ? -seg0 : OFF) : NEG;
            int io1 = (cb + 1 < 32) ? OFF : NEG;   // window crossing implies cb==ch0
            int key_prev = -1;
            float acc = 0.f;
            #pragma unroll
            for (int j = 0; j < 32; ++j) {
                int io = (j < jcross) ? io0 : io1;
                if (io != NEG) {
                    int key = io + (int)seg_s[w * SEG_STR + j];
                    if (key != key_prev) {
                        if (key_prev >= 0) atomicAdd(&tile[b * TILE_K + key_prev], acc);
                        key_prev = key;
                        acc = vv[j];
                    } else {
                        acc += vv[j];
                    }
                }
            }
            if (key_prev >= 0) atomicAdd(&tile[b * TILE_K + key_prev], acc);
        } else {
            // fallback (never expected at E/1024 ~ 45 items/key): direct atomics
            int base0 = (cb < 32)     ? ((b << 15) | (cb << 10))       : -1;
            int base1 = (cb + 1 < 32) ? ((b << 15) | ((cb + 1) << 10)) : -1;
            int key_prev = -1;
            float acc = 0.f;
            #pragma unroll
            for (int j = 0; j < 32; ++j) {
                int basej = (j < jcross) ? base0 : base1;
                if (basej >= 0) {
                    int key = basej + (int)seg_s[w * SEG_STR + j];
                    if (key != key_prev) {
                        if (key_prev >= 0) atomicAdd(&out[key_prev], acc);
                        key_prev = key;
                        acc = vv[j];
                    } else {
                        acc += vv[j];
                    }
                }
            }
            if (key_prev >= 0) atomicAdd(&out[key_prev], acc);
        }
    }

    if (NK <= TILE_K) {
        __syncthreads();   // S6: all E1 tile atomics done

        // ---- E2: flattened coalesced writeback, one key per thread ----
        int total = NK * 16;
        for (int t = tid; t < total; t += 512) {
            int bb = t / NK;               // runtime div, 1-5 iters total
            int i  = t - bb * NK;
            int cbx, sg;
            if (wrap && i >= OFF) { cbx = ch0 + 1; sg = i - OFF; }
            else                  { cbx = ch0;     sg = seg0 + i; }
            if (cbx < 32) {
                float v = tile[bb * TILE_K + i];
                int o = (bb << 15) | (cbx << 10) | sg;
                bool bnd = (i == 0) || (i == NK - 1) ||
                           (wrap && (i == OFF - 1 || i == OFF));
                if (bnd) atomicAdd(&out[o], v);
                else     out[o] = v;
            }
        }
    }
}

// ---------------------------------------------------------------------------
// Fallback: round-1 fused kernel (used only if ws too small)
// ---------------------------------------------------------------------------
__global__ __launch_bounds__(256, 2)
void qc_main_kernel(const float* __restrict__ feat,
                    const float* __restrict__ w1,
                    const float* __restrict__ w2,
                    const float* __restrict__ locs,
                    const int*   __restrict__ eidx,
                    const __bf16* __restrict__ w3t,
                    float* __restrict__ out,
                    int E)
{
    __shared__ __align__(16) __bf16 h1b[ROWS * H1_STR];
    __shared__ __align__(16) __bf16 h2b[ROWS * H2_STR];
    __shared__ __align__(16) __bf16 ftv[ROWS * FB_FT_NSTR];
    __shared__ __align__(16) __bf16 gb [BATCH * G_STR];
    __shared__ unsigned short seg_s[512];
    __shared__ unsigned short src_s[512];

    const int tid = threadIdx.x;
    const int n0  = blockIdx.x * ROWS;
    const int t0  = n0 * 32;
    const int ch0 = t0 / E;
    const int m0  = t0 - ch0 * E;

    {
        const int r  = tid >> 4;
        const int j0 = (tid & 15) * 4;
        float lx = 0.f, ly = 0.f;
        int n = n0 + r;
        if (n < E) { lx = locs[n * 2]; ly = locs[n * 2 + 1]; }
        float4 wa = *(const float4*)&w1[j0];
        float4 wb = *(const float4*)&w1[64 + j0];
        __bf16* h = &h1b[r * H1_STR + j0];
        h[0] = (__bf16)__sinf(lx * wa.x + ly * wb.x);
        h[1] = (__bf16)__sinf(lx * wa.y + ly * wb.y);
        h[2] = (__bf16)__sinf(lx * wa.z + ly * wb.z);
        h[3] = (__bf16)__sinf(lx * wa.w + ly * wb.w);
    }
    for (int tl = tid; tl < 512; tl += 256) {
        int mm = m0 + tl; if (mm >= E) mm -= E;
        seg_s[tl] = (unsigned short)eidx[mm * 2];
        src_s[tl] = (unsigned short)eidx[mm * 2 + 1];
    }
    __syncthreads();

    {
        const int r  = tid >> 4;
        const int j0 = (tid & 15) * 4;
        float a0 = 0.f, a1 = 0.f, a2 = 0.f, a3 = 0.f;
        const __bf16* h1r = &h1b[r * H1_STR];
        #pragma unroll 8
        for (int k = 0; k < 64; ++k) {
            float h = (float)h1r[k];
            float4 w = *(const float4*)&w2[k * 64 + j0];
            a0 += h * w.x; a1 += h * w.y; a2 += h * w.z; a3 += h * w.w;
        }
        __bf16* h = &h2b[r * H2_STR + j0];
        h[0] = (__bf16)__sinf(a0);
        h[1] = (__bf16)__sinf(a1);
        h[2] = (__bf16)__sinf(a2);
        h[3] = (__bf16)__sinf(a3);
    }
    #pragma unroll 4
    for (int it = 0; it < 32; ++it) {
        int idx = it * 256 + tid;
        int b   = idx >> 9;
        int tl  = idx & 511;
        int mm  = m0 + tl;
        int cc  = ch0 + (mm >= E);
        if (mm >= E) mm -= E;
        float v = 0.f;
        if (cc < 32) v = feat[(b * 32 + cc) * N_IN + (int)src_s[tl]];
        gb[b * G_STR + tl] = (__bf16)v;
    }
    __syncthreads();

    const int lane = tid & 63;
    const int wv   = tid >> 6;
    const int ml   = lane & 15;
    const int q    = lane >> 4;

    {
        bf16x8 a0 = *(const bf16x8*)&h2b[ml * H2_STR + q * 8];
        bf16x8 a1 = *(const bf16x8*)&h2b[ml * H2_STR + 32 + q * 8];
        #pragma unroll
        for (int t = 0; t < 16; ++t) {
            int col = wv * 256 + t * 16 + ml;
            const __bf16* wp = &w3t[col * 64 + q * 8];
            bf16x8 b0 = *(const bf16x8*)wp;
            bf16x8 b1 = *(const bf16x8*)(wp + 32);
            f32x4 c = {0.f, 0.f, 0.f, 0.f};
            c = __builtin_amdgcn_mfma_f32_16x16x32_bf16(a0, b0, c, 0, 0, 0);
            c = __builtin_amdgcn_mfma_f32_16x16x32_bf16(a1, b1, c, 0, 0, 0);
            int i_ = col >> 5, j_ = col & 31;
            __bf16* fp = &ftv[j_ * FT_JSTR + i_];
            fp[(q * 4 + 0) * FB_FT_NSTR] = (__bf16)c[0];
            fp[(q * 4 + 1) * FB_FT_NSTR] = (__bf16)c[1];
            fp[(q * 4 + 2) * FB_FT_NSTR] = (__bf16)c[2];
            fp[(q * 4 + 3) * FB_FT_NSTR] = (__bf16)c[3];
        }
    }
    __syncthreads();

    {
        bf16x8 ag[4], f0[4], f1[4];
        #pragma unroll
        for (int rr = 0; rr < 4; ++rr) {
            int r = wv * 4 + rr;
            ag[rr] = *(const bf16x8*)&gb[ml * G_STR + r * 32 + q * 8];
            f0[rr] = *(const bf16x8*)&ftv[r * FB_FT_NSTR + ml        * FT_JSTR + q * 8];
            f1[rr] = *(const bf16x8*)&ftv[r * FB_FT_NSTR + (16 + ml) * FT_JSTR + q * 8];
        }
        __syncthreads();
        __bf16* valsb = ftv;
        #pragma unroll
        for (int rr = 0; rr < 4; ++rr) {
            int r = wv * 4 + rr;
            f32x4 c0 = {0.f, 0.f, 0.f, 0.f};
            f32x4 c1 = {0.f, 0.f, 0.f, 0.f};
            c0 = __builtin_amdgcn_mfma_f32_16x16x32_bf16(ag[rr], f0[rr], c0, 0, 0, 0);
            c1 = __builtin_amdgcn_mfma_f32_16x16x32_bf16(ag[rr], f1[rr], c1, 0, 0, 0);
            __bf16* vp = &valsb[r * 32];
            #pragma unroll
            for (int g_ = 0; g_ < 4; ++g_) {
                int b = q * 4 + g_;
                vp[b * V_STR + ml]      = (__bf16)c0[g_];
                vp[b * V_STR + 16 + ml] = (__bf16)c1[g_];
            }
        }
    }
    __syncthreads();

    {
        const __bf16* valsb = ftv;
        const int b = tid >> 4;
        const int r = tid & 15;
        const __bf16* vp = &valsb[b * V_STR + r * 32];
        bf16x8 v0 = *(const bf16x8*)(vp);
        bf16x8 v1 = *(const bf16x8*)(vp + 8);
        bf16x8 v2 = *(const bf16x8*)(vp + 16);
        bf16x8 v3 = *(const bf16x8*)(vp + 24);
        float vv[32];
        #pragma unroll
        for (int j = 0; j < 8; ++j) {
            vv[j]      = (float)v0[j];
            vv[8 + j]  = (float)v1[j];
            vv[16 + j] = (float)v2[j];
            vv[24 + j] = (float)v3[j];
        }
        const int tl0 = r * 32;
        int key_prev = -1;
        float acc = 0.f;
        #pragma unroll
        for (int j = 0; j < 32; ++j) {
            int mm = m0 + tl0 + j;
            int cc = ch0 + (mm >= E);
            if (mm >= E) mm -= E;
            if (cc < 32) {
                int o   = (int)seg_s[tl0 + j];
                int key = ((b * 32 + cc) << 10) | o;
                if (key != key_prev) {
                    if (key_prev >= 0) atomicAdd(&out[key_prev], acc);
                    key_prev = key;
                    acc = vv[j];
                } else {
                    acc += vv[j];
                }
            }
        }
        if (key_prev >= 0) atomicAdd(&out[key_prev], acc);
    }
}

extern "C" void kernel_launch(void* const* d_in, const int* in_sizes, int n_in,
                              void* d_out, int out_size, void* d_ws, size_t ws_size,
                              hipStream_t stream)
{
    (void)n_in;
    const float* feat = (const float*)d_in[0];
    const float* w1   = (const float*)d_in[1];
    const float* w2   = (const float*)d_in[2];
    const float* w3   = (const float*)d_in[3];
    const float* locs = (const float*)d_in[4];
    const int*   eidx = (const int*)d_in[5];
    float* out  = (float*)d_out;

    const int E = in_sizes[4] / 2;
    if (E <= 0) return;

    __bf16* w3t   = (__bf16*)((char*)d_ws + WS_W3T_OFF);
    __bf16* w2t   = (__bf16*)((char*)d_ws + WS_W2T_OFF);
    __bf16* featT = (__bf16*)((char*)d_ws + WS_FEATT_OFF);

    if (ws_size >= (size_t)WS_NEED) {
        int nblocks = (E + 31) / 32;
        qc_prep2_kernel<<<1041, 256, 0, stream>>>(w3, w2, feat, out, w3t, w2t, featT);
        qc_fused32_kernel<<<nblocks, 512, 0, stream>>>(featT, w1, locs, eidx, w2t, w3t, out, E);
    } else {
        int n4 = out_size / 4;
        int nblocks = (E + ROWS - 1) / ROWS;
        qc_zero_kernel<<<(n4 + 255) / 256, 256, 0, stream>>>(out, n4);
        qc_prep_kernel<<<272, 256, 0, stream>>>(w3, w2, w3t, w2t);
        qc_main_kernel<<<nblocks, 256, 0, stream>>>(feat, w1, w2, locs, eidx, w3t, out, E);
    }
}